// Round 3
// baseline (2824.477 us; speedup 1.0000x reference)
//
#include <hip/hip_runtime.h>

// GIN forward, bucketed edition.
// lin0 -> 3x [GINConv(sum-agg) -> Lin->BN->ReLU->Lin->BN->ReLU] -> mean-pool
// N=100000, E=1.6M, D=49 (pad LD=64), NG=512.
//
// vs round 1 (scatter was 120us with 107MB writes):
//  - dst-bucketed edge layout (128 nodes/bucket, NB=782): LDS histogram (200K global
//    atomics vs 1.6M), per-(block,bucket) range reservation, packed 4B edge records
//    (src | dstLocal<<20) written in short contiguous runs -> ~15MB writes.
//  - aggregation fused per bucket: LDS [128][64] f32 tile accumulated with ds_add_f32
//    (lane-consecutive -> 2-way bank alias, free), BN+ReLU of the PREVIOUS layer folded
//    into the gather -> k_bnrelu eliminated, one h round-trip per layer saved.
//  - GEMM: input row preloaded to registers via 13x float4 (L1-friendly) instead of
//    49 strided scalar loads (L1 thrash -> L2 refetch each k).
//  - pool folds final BN+ReLU.
//  - this round: 8-deep gather ILP in k_aggc (latency-critical path).

#define DV 49
#define LD 64
#define DIN 56
#define NGR 512
#define NLAY 3
#define BSH 7
#define BSZ 128
#define MAXNB 1024  // supports N <= 131072

__global__ void k_zero(int* __restrict__ ghist, int NB, float* __restrict__ stats) {
    int i = blockIdx.x * blockDim.x + threadIdx.x;
    int stride = gridDim.x * blockDim.x;
    for (int j = i; j < NB; j += stride) ghist[j] = 0;
    for (int j = i; j < NLAY * 2 * 128; j += stride) stats[j] = 0.f;
}

__global__ void k_hist_b(const int* __restrict__ dst, int E, int* __restrict__ ghist, int NB) {
    __shared__ int lh[MAXNB];
    int t = threadIdx.x;
    for (int i = t; i < NB; i += 256) lh[i] = 0;
    __syncthreads();
    int chunk = (E + gridDim.x - 1) / gridDim.x;
    int s = blockIdx.x * chunk, e = min(E, s + chunk);
    for (int i = s + t; i < e; i += 256) atomicAdd(&lh[dst[i] >> BSH], 1);
    __syncthreads();
    for (int i = t; i < NB; i += 256)
        if (lh[i]) atomicAdd(&ghist[i], lh[i]);
}

__global__ void k_scanb(const int* __restrict__ g, int NB, int* __restrict__ bstart,
                        int* __restrict__ cursor) {
    __shared__ int sm[256];
    __shared__ int carry;
    int t = threadIdx.x;
    if (t == 0) carry = 0;
    __syncthreads();
    for (int base = 0; base < NB; base += 256) {
        int v = (base + t < NB) ? g[base + t] : 0;
        sm[t] = v;
        __syncthreads();
        for (int off = 1; off < 256; off <<= 1) {
            int x = (t >= off) ? sm[t - off] : 0;
            __syncthreads();
            sm[t] += x;
            __syncthreads();
        }
        int excl = sm[t] - v + carry;
        if (base + t < NB) { bstart[base + t] = excl; cursor[base + t] = excl; }
        int tot = sm[255];
        __syncthreads();
        if (t == 0) carry += tot;
        __syncthreads();
    }
    if (t == 0) bstart[NB] = carry;
}

__global__ void k_scatter_b(const int* __restrict__ src, const int* __restrict__ dst, int E,
                            int* __restrict__ cursor, unsigned int* __restrict__ ep, int NB) {
    __shared__ int lcount[MAXNB];
    __shared__ int lbase[MAXNB];
    __shared__ int lofs[MAXNB];
    int t = threadIdx.x;
    for (int i = t; i < NB; i += 256) { lcount[i] = 0; lofs[i] = 0; }
    __syncthreads();
    int chunk = (E + gridDim.x - 1) / gridDim.x;
    int s = blockIdx.x * chunk, e = min(E, s + chunk);
    for (int i = s + t; i < e; i += 256) atomicAdd(&lcount[dst[i] >> BSH], 1);
    __syncthreads();
    for (int i = t; i < NB; i += 256)
        if (lcount[i]) lbase[i] = atomicAdd(&cursor[i], lcount[i]);
    __syncthreads();
    for (int i = s + t; i < e; i += 256) {
        int d = dst[i];
        int b = d >> BSH;
        int pos = lbase[b] + atomicAdd(&lofs[b], 1);
        ep[pos] = (unsigned)src[i] | ((unsigned)(d & (BSZ - 1)) << 20);
    }
}

__global__ void k_lin0(const float* __restrict__ x, const float* __restrict__ W0,
                       const float* __restrict__ b0, float* __restrict__ h, int N) {
    __shared__ __align__(16) float Ws[DIN * 52];
    __shared__ float pb[52];
    int t = threadIdx.x;
    for (int i = t; i < DIN * 52; i += 256) {
        int k = i / 52, c = i - k * 52;
        Ws[i] = (c < DV) ? W0[k * DV + c] : 0.f;
    }
    for (int i = t; i < 52; i += 256) pb[i] = (i < DV) ? b0[i] : 0.f;
    __syncthreads();
    int n = blockIdx.x * 256 + t;
    if (n >= N) return;
    float row[DIN];
    const float* xr = x + (size_t)n * DIN;
#pragma unroll
    for (int q = 0; q < DIN / 4; q++) {
        float4 v = *(const float4*)&xr[q * 4];
        row[q * 4 + 0] = v.x; row[q * 4 + 1] = v.y;
        row[q * 4 + 2] = v.z; row[q * 4 + 3] = v.w;
    }
    float acc[52];
#pragma unroll
    for (int c = 0; c < 52; c++) acc[c] = pb[c];
    for (int k = 0; k < DIN; k++) {
        float xv = row[k];
#pragma unroll
        for (int c4 = 0; c4 < 13; c4++) {
            float4 w = *(const float4*)&Ws[k * 52 + c4 * 4];
            acc[c4 * 4 + 0] = fmaf(xv, w.x, acc[c4 * 4 + 0]);
            acc[c4 * 4 + 1] = fmaf(xv, w.y, acc[c4 * 4 + 1]);
            acc[c4 * 4 + 2] = fmaf(xv, w.z, acc[c4 * 4 + 2]);
            acc[c4 * 4 + 3] = fmaf(xv, w.w, acc[c4 * 4 + 3]);
        }
    }
    float* hr = h + (size_t)n * LD;
#pragma unroll
    for (int c4 = 0; c4 < 13; c4++) {
        float4 o;
        o.x = acc[c4 * 4 + 0]; o.y = acc[c4 * 4 + 1];
        o.z = acc[c4 * 4 + 2]; o.w = acc[c4 * 4 + 3];
        *(float4*)&hr[c4 * 4] = o;
    }
    float4 zz = make_float4(0.f, 0.f, 0.f, 0.f);
    *(float4*)&hr[52] = zz;
    *(float4*)&hr[56] = zz;
    *(float4*)&hr[60] = zz;
}

// One block per 128-node bucket. Accumulate neighbor rows into LDS tile via ds_add_f32;
// BN+ReLU of the previous layer folded into the gather (BN_IN). Self term + coalesced write.
template <bool BN_IN>
__global__ void k_aggc(const float* __restrict__ hin, float* __restrict__ zout,
                       const unsigned int* __restrict__ ep, const int* __restrict__ bstart,
                       const float* __restrict__ gam, const float* __restrict__ bet,
                       const float* __restrict__ stats, float invN,
                       const float* __restrict__ eps_gin, int l, int N) {
    __shared__ float acc[BSZ * LD];  // 32 KB
    __shared__ float scs[LD], shs[LD];
    int t = threadIdx.x;
    for (int i = t; i < BSZ * LD; i += 256) acc[i] = 0.f;
    if (BN_IN && t < LD) {
        if (t < DV) {
            float mu = stats[t] * invN;
            float var = stats[64 + t] * invN - mu * mu;
            float s = gam[t] * rsqrtf(var + 1e-5f);
            scs[t] = s;
            shs[t] = bet[t] - mu * s;
        } else {
            scs[t] = 0.f;
            shs[t] = 0.f;
        }
    }
    __syncthreads();
    int b = blockIdx.x;
    int es = bstart[b], ee = bstart[b + 1];
    int wave = t >> 6, lane = t & 63;
    float scr = BN_IN ? scs[lane] : 1.f;
    float shr = BN_IN ? shs[lane] : 0.f;
    for (int base = es + wave * 64; base < ee; base += 256) {
        int m = min(64, ee - base);
        int pk = (lane < m) ? (int)ep[base + lane] : 0;
        int e = 0;
        for (; e + 8 <= m; e += 8) {
            unsigned p0 = (unsigned)__shfl(pk, e);
            unsigned p1 = (unsigned)__shfl(pk, e + 1);
            unsigned p2 = (unsigned)__shfl(pk, e + 2);
            unsigned p3 = (unsigned)__shfl(pk, e + 3);
            unsigned p4 = (unsigned)__shfl(pk, e + 4);
            unsigned p5 = (unsigned)__shfl(pk, e + 5);
            unsigned p6 = (unsigned)__shfl(pk, e + 6);
            unsigned p7 = (unsigned)__shfl(pk, e + 7);
            float v0 = hin[(size_t)(p0 & 0xFFFFFu) * LD + lane];
            float v1 = hin[(size_t)(p1 & 0xFFFFFu) * LD + lane];
            float v2 = hin[(size_t)(p2 & 0xFFFFFu) * LD + lane];
            float v3 = hin[(size_t)(p3 & 0xFFFFFu) * LD + lane];
            float v4 = hin[(size_t)(p4 & 0xFFFFFu) * LD + lane];
            float v5 = hin[(size_t)(p5 & 0xFFFFFu) * LD + lane];
            float v6 = hin[(size_t)(p6 & 0xFFFFFu) * LD + lane];
            float v7 = hin[(size_t)(p7 & 0xFFFFFu) * LD + lane];
            if (BN_IN) {
                v0 = fmaxf(0.f, fmaf(v0, scr, shr));
                v1 = fmaxf(0.f, fmaf(v1, scr, shr));
                v2 = fmaxf(0.f, fmaf(v2, scr, shr));
                v3 = fmaxf(0.f, fmaf(v3, scr, shr));
                v4 = fmaxf(0.f, fmaf(v4, scr, shr));
                v5 = fmaxf(0.f, fmaf(v5, scr, shr));
                v6 = fmaxf(0.f, fmaf(v6, scr, shr));
                v7 = fmaxf(0.f, fmaf(v7, scr, shr));
            }
            atomicAdd(&acc[(p0 >> 20) * LD + lane], v0);
            atomicAdd(&acc[(p1 >> 20) * LD + lane], v1);
            atomicAdd(&acc[(p2 >> 20) * LD + lane], v2);
            atomicAdd(&acc[(p3 >> 20) * LD + lane], v3);
            atomicAdd(&acc[(p4 >> 20) * LD + lane], v4);
            atomicAdd(&acc[(p5 >> 20) * LD + lane], v5);
            atomicAdd(&acc[(p6 >> 20) * LD + lane], v6);
            atomicAdd(&acc[(p7 >> 20) * LD + lane], v7);
        }
        for (; e < m; e++) {
            unsigned p = (unsigned)__shfl(pk, e);
            float v = hin[(size_t)(p & 0xFFFFFu) * LD + lane];
            if (BN_IN) v = fmaxf(0.f, fmaf(v, scr, shr));
            atomicAdd(&acc[(p >> 20) * LD + lane], v);
        }
    }
    __syncthreads();
    float eps1 = 1.f + eps_gin[l];
    int nb0 = b << BSH;
    for (int i = t; i < BSZ * LD; i += 256) {
        int row = i >> 6, col = i & 63;
        int n = nb0 + row;
        if (n < N) {
            float sv = hin[(size_t)n * LD + col];
            if (BN_IN) sv = fmaxf(0.f, fmaf(sv, scs[col], shs[col]));
            zout[(size_t)n * LD + col] = acc[i] + eps1 * sv;
        }
    }
}

// One thread per row; input row preloaded to registers (13x float4). Optional BN+ReLU of
// the input (stats of the previous linear); column sum/sumsq of output for the next BN.
template <bool BN_IN>
__global__ void k_gemm(const float* in, float* out,
                       const float* __restrict__ W, const float* __restrict__ bias,
                       const float* __restrict__ gam, const float* __restrict__ bet,
                       const float* __restrict__ statsIn, float* __restrict__ statsOut,
                       float invN, int N) {
    __shared__ __align__(16) float Ws[DV * 52];
    __shared__ float pb[52];
    __shared__ float sc[DV], sh[DV];
    int t = threadIdx.x;
    for (int i = t; i < DV * 52; i += 256) {
        int k = i / 52, c = i - k * 52;
        Ws[i] = (c < DV) ? W[k * DV + c] : 0.f;
    }
    for (int i = t; i < 52; i += 256) pb[i] = (i < DV) ? bias[i] : 0.f;
    if (BN_IN) {
        if (t < DV) {
            float mu = statsIn[t] * invN;
            float var = statsIn[64 + t] * invN - mu * mu;
            float s = gam[t] * rsqrtf(var + 1e-5f);
            sc[t] = s;
            sh[t] = bet[t] - mu * s;
        }
    }
    __syncthreads();
    int n = blockIdx.x * 256 + t;
    bool active = (n < N);
    float row[52];
    if (active) {
        const float* rp = in + (size_t)n * LD;
#pragma unroll
        for (int q = 0; q < 13; q++) {
            float4 v = *(const float4*)&rp[q * 4];
            row[q * 4 + 0] = v.x; row[q * 4 + 1] = v.y;
            row[q * 4 + 2] = v.z; row[q * 4 + 3] = v.w;
        }
        if (BN_IN) {
#pragma unroll
            for (int k = 0; k < DV; k++) row[k] = fmaxf(0.f, fmaf(row[k], sc[k], sh[k]));
        }
    } else {
#pragma unroll
        for (int q = 0; q < 52; q++) row[q] = 0.f;
    }
    float acc[52];
#pragma unroll
    for (int c = 0; c < 52; c++) acc[c] = pb[c];
    for (int k = 0; k < DV; k++) {
        float xv = row[k];
#pragma unroll
        for (int c4 = 0; c4 < 13; c4++) {
            float4 w = *(const float4*)&Ws[k * 52 + c4 * 4];
            acc[c4 * 4 + 0] = fmaf(xv, w.x, acc[c4 * 4 + 0]);
            acc[c4 * 4 + 1] = fmaf(xv, w.y, acc[c4 * 4 + 1]);
            acc[c4 * 4 + 2] = fmaf(xv, w.z, acc[c4 * 4 + 2]);
            acc[c4 * 4 + 3] = fmaf(xv, w.w, acc[c4 * 4 + 3]);
        }
    }
    if (active) {
        float* orow = out + (size_t)n * LD;
#pragma unroll
        for (int c4 = 0; c4 < 13; c4++) {
            float4 o;
            o.x = acc[c4 * 4 + 0]; o.y = acc[c4 * 4 + 1];
            o.z = acc[c4 * 4 + 2]; o.w = acc[c4 * 4 + 3];
            *(float4*)&orow[c4 * 4] = o;
        }
        float4 zz = make_float4(0.f, 0.f, 0.f, 0.f);
        *(float4*)&orow[52] = zz;
        *(float4*)&orow[56] = zz;
        *(float4*)&orow[60] = zz;
    }
    // wave butterfly per column; lane c keeps column c's totals; 2 atomics/wave.
    float myS = 0.f, myQ = 0.f;
    int lane = t & 63;
#pragma unroll
    for (int c = 0; c < DV; c++) {
        float v = active ? acc[c] : 0.f;
        float s = v, q = v * v;
#pragma unroll
        for (int off = 32; off > 0; off >>= 1) {
            s += __shfl_xor(s, off);
            q += __shfl_xor(q, off);
        }
        if (lane == c) { myS = s; myQ = q; }
    }
    if (lane < DV) {
        atomicAdd(&statsOut[lane], myS);
        atomicAdd(&statsOut[64 + lane], myQ);
    }
}

// batch sorted: one wave per graph, binary search range, fold final BN+ReLU.
__global__ void k_pool(const float* __restrict__ h, const int* __restrict__ batch,
                       const float* __restrict__ gam, const float* __restrict__ bet,
                       const float* __restrict__ stats, float invN,
                       float* __restrict__ out, int N) {
    int g = blockIdx.x;
    int lane = threadIdx.x;
    int lo, hi;
    {
        int a = 0, b = N;
        while (a < b) { int mid = (a + b) >> 1; if (batch[mid] < g) a = mid + 1; else b = mid; }
        lo = a;
    }
    {
        int a = lo, b = N;
        while (a < b) { int mid = (a + b) >> 1; if (batch[mid] < g + 1) a = mid + 1; else b = mid; }
        hi = a;
    }
    float scv = 0.f, shv = 0.f;
    if (lane < DV) {
        float mu = stats[lane] * invN;
        float var = stats[64 + lane] * invN - mu * mu;
        float s = gam[lane] * rsqrtf(var + 1e-5f);
        scv = s;
        shv = bet[lane] - mu * s;
    }
    float a0 = 0.f, a1 = 0.f, a2 = 0.f, a3 = 0.f;
    int n2 = lo;
    for (; n2 + 4 <= hi; n2 += 4) {
        a0 += fmaxf(0.f, fmaf(h[(size_t)(n2 + 0) * LD + lane], scv, shv));
        a1 += fmaxf(0.f, fmaf(h[(size_t)(n2 + 1) * LD + lane], scv, shv));
        a2 += fmaxf(0.f, fmaf(h[(size_t)(n2 + 2) * LD + lane], scv, shv));
        a3 += fmaxf(0.f, fmaf(h[(size_t)(n2 + 3) * LD + lane], scv, shv));
    }
    for (; n2 < hi; n2++)
        a0 += fmaxf(0.f, fmaf(h[(size_t)n2 * LD + lane], scv, shv));
    float acc = (a0 + a1) + (a2 + a3);
    float cnt = (float)max(hi - lo, 1);
    if (lane < DV) out[g * DV + lane] = acc / cnt;
}

extern "C" void kernel_launch(void* const* d_in, const int* in_sizes, int n_in,
                              void* d_out, int out_size, void* d_ws, size_t ws_size,
                              hipStream_t stream) {
    const float* x = (const float*)d_in[0];
    const float* W0 = (const float*)d_in[1];
    const float* b0 = (const float*)d_in[2];
    const float* W1 = (const float*)d_in[3];
    const float* b1 = (const float*)d_in[4];
    const float* g1 = (const float*)d_in[5];
    const float* be1 = (const float*)d_in[6];
    const float* W2 = (const float*)d_in[7];
    const float* b2 = (const float*)d_in[8];
    const float* g2 = (const float*)d_in[9];
    const float* be2 = (const float*)d_in[10];
    const float* eps_gin = (const float*)d_in[11];
    const int* edge_index = (const int*)d_in[12];
    const int* batch = (const int*)d_in[13];
    float* out = (float*)d_out;

    int N = in_sizes[0] / DIN;
    int E = in_sizes[12] / 2;
    const int* esrc = edge_index;
    const int* edst = edge_index + E;
    int NB = (N + BSZ - 1) >> BSH;

    char* ws = (char*)d_ws;
    size_t off = 0;
    auto alloc = [&](size_t bytes) -> void* {
        void* p = ws + off;
        off = (off + bytes + 255) & ~(size_t)255;
        return p;
    };
    float* P = (float*)alloc((size_t)N * LD * 4);   // activations (ping)
    float* A = (float*)alloc((size_t)N * LD * 4);   // activations (pong)
    unsigned int* ep = (unsigned int*)alloc((size_t)E * 4);
    int* ghist = (int*)alloc((size_t)NB * 4);
    int* bstart = (int*)alloc((size_t)(NB + 1) * 4);
    int* cursor = (int*)alloc((size_t)NB * 4);
    float* stats = (float*)alloc(NLAY * 2 * 128 * 4);
    (void)ws_size;  // needs ~58 MB

    float invN = 1.f / (float)N;
    int gN = (N + 255) / 256;

    k_zero<<<8, 256, 0, stream>>>(ghist, NB, stats);
    k_hist_b<<<256, 256, 0, stream>>>(edst, E, ghist, NB);
    k_scanb<<<1, 256, 0, stream>>>(ghist, NB, bstart, cursor);
    k_scatter_b<<<256, 256, 0, stream>>>(esrc, edst, E, cursor, ep, NB);
    k_lin0<<<gN, 256, 0, stream>>>(x, W0, b0, P, N);

    for (int l = 0; l < NLAY; l++) {
        float* S1 = stats + (l * 2 + 0) * 128;
        float* S2 = stats + (l * 2 + 1) * 128;
        if (l == 0) {
            k_aggc<false><<<NB, 256, 0, stream>>>(P, A, ep, bstart, nullptr, nullptr,
                                                  nullptr, invN, eps_gin, l, N);
        } else {
            float* S2p = stats + ((l - 1) * 2 + 1) * 128;
            k_aggc<true><<<NB, 256, 0, stream>>>(P, A, ep, bstart, g2 + (l - 1) * DV,
                                                 be2 + (l - 1) * DV, S2p, invN, eps_gin, l, N);
        }
        k_gemm<false><<<gN, 256, 0, stream>>>(A, A, W1 + (size_t)l * DV * DV, b1 + l * DV,
                                              nullptr, nullptr, nullptr, S1, invN, N);
        k_gemm<true><<<gN, 256, 0, stream>>>(A, P, W2 + (size_t)l * DV * DV, b2 + l * DV,
                                             g1 + l * DV, be1 + l * DV, S1, S2, invN, N);
    }
    float* S2last = stats + ((NLAY - 1) * 2 + 1) * 128;
    k_pool<<<NGR, 64, 0, stream>>>(P, batch, g2 + (NLAY - 1) * DV, be2 + (NLAY - 1) * DV,
                                   S2last, invN, out, N);
}

// Round 5
// 930.204 us; speedup vs baseline: 3.0364x; 3.0364x over previous
//
#include <hip/hip_runtime.h>

// GIN forward. lin0 -> 3x [GINConv(sum-agg) -> Lin->BN->ReLU->Lin->BN->ReLU] -> mean-pool
// N=100000, E=1.6M, D=49 (pad LD=64), NG=512.
//
// Round-4/5: bucketed preprocessing (kept — fixed the 107MB scatter amplification) now
// feeds a within-bucket counting sort (k_sortb) that emits a true per-node CSR.
// Aggregation reverts to ONE WAVE PER NODE (25000 blocks, no LDS): round-3's
// one-block-per-bucket LDS-tile version collapsed occupancy to 22% (3 blocks/CU
// at 32.5KB LDS) and ran 718us/layer at 3.4% VALUBusy — the random gather is
// latency-bound and needs wave count, not LDS reuse. BN+ReLU of the previous
// layer stays folded into the gather; GEMMs/pool unchanged.

#define DV 49
#define LD 64
#define DIN 56
#define NGR 512
#define NLAY 3
#define BSH 7
#define BSZ 128
#define MAXNB 1024  // supports N <= 131072

__global__ void k_zero(int* __restrict__ ghist, int NB, float* __restrict__ stats) {
    int i = blockIdx.x * blockDim.x + threadIdx.x;
    int stride = gridDim.x * blockDim.x;
    for (int j = i; j < NB; j += stride) ghist[j] = 0;
    for (int j = i; j < NLAY * 2 * 128; j += stride) stats[j] = 0.f;
}

__global__ void k_hist_b(const int* __restrict__ dst, int E, int* __restrict__ ghist, int NB) {
    __shared__ int lh[MAXNB];
    int t = threadIdx.x;
    for (int i = t; i < NB; i += 256) lh[i] = 0;
    __syncthreads();
    int chunk = (E + gridDim.x - 1) / gridDim.x;
    int s = blockIdx.x * chunk, e = min(E, s + chunk);
    for (int i = s + t; i < e; i += 256) atomicAdd(&lh[dst[i] >> BSH], 1);
    __syncthreads();
    for (int i = t; i < NB; i += 256)
        if (lh[i]) atomicAdd(&ghist[i], lh[i]);
}

__global__ void k_scanb(const int* __restrict__ g, int NB, int* __restrict__ bstart,
                        int* __restrict__ cursor) {
    __shared__ int sm[256];
    __shared__ int carry;
    int t = threadIdx.x;
    if (t == 0) carry = 0;
    __syncthreads();
    for (int base = 0; base < NB; base += 256) {
        int v = (base + t < NB) ? g[base + t] : 0;
        sm[t] = v;
        __syncthreads();
        for (int off = 1; off < 256; off <<= 1) {
            int x = (t >= off) ? sm[t - off] : 0;
            __syncthreads();
            sm[t] += x;
            __syncthreads();
        }
        int excl = sm[t] - v + carry;
        if (base + t < NB) { bstart[base + t] = excl; cursor[base + t] = excl; }
        int tot = sm[255];
        __syncthreads();
        if (t == 0) carry += tot;
        __syncthreads();
    }
    if (t == 0) bstart[NB] = carry;
}

__global__ void k_scatter_b(const int* __restrict__ src, const int* __restrict__ dst, int E,
                            int* __restrict__ cursor, unsigned int* __restrict__ ep, int NB) {
    __shared__ int lcount[MAXNB];
    __shared__ int lbase[MAXNB];
    __shared__ int lofs[MAXNB];
    int t = threadIdx.x;
    for (int i = t; i < NB; i += 256) { lcount[i] = 0; lofs[i] = 0; }
    __syncthreads();
    int chunk = (E + gridDim.x - 1) / gridDim.x;
    int s = blockIdx.x * chunk, e = min(E, s + chunk);
    for (int i = s + t; i < e; i += 256) atomicAdd(&lcount[dst[i] >> BSH], 1);
    __syncthreads();
    for (int i = t; i < NB; i += 256)
        if (lcount[i]) lbase[i] = atomicAdd(&cursor[i], lcount[i]);
    __syncthreads();
    for (int i = s + t; i < e; i += 256) {
        int d = dst[i];
        int b = d >> BSH;
        int pos = lbase[b] + atomicAdd(&lofs[b], 1);
        ep[pos] = (unsigned)src[i] | ((unsigned)(d & (BSZ - 1)) << 20);
    }
}

// One block per bucket: counting-sort packed records by dstLocal -> per-node CSR + rowptr.
__global__ void k_sortb(const unsigned int* __restrict__ ep, const int* __restrict__ bstart,
                        int* __restrict__ csr, int* __restrict__ rowptr, int N, int NB) {
    __shared__ int cnt[BSZ];
    __shared__ int pref[BSZ];
    int t = threadIdx.x;
    int b = blockIdx.x;
    int es = bstart[b], ee = bstart[b + 1];
    if (t < BSZ) cnt[t] = 0;
    __syncthreads();
    for (int i = es + t; i < ee; i += 256) atomicAdd(&cnt[(ep[i] >> 20) & 127], 1);
    __syncthreads();
    if (t < BSZ) pref[t] = cnt[t];
    __syncthreads();
    for (int off = 1; off < BSZ; off <<= 1) {
        int x = 0;
        if (t < BSZ && t >= off) x = pref[t - off];
        __syncthreads();
        if (t < BSZ && t >= off) pref[t] += x;
        __syncthreads();
    }
    // exclusive prefix
    if (t < BSZ) pref[t] -= cnt[t];
    __syncthreads();
    if (t < BSZ) {
        int n = (b << BSH) + t;
        if (n < N) rowptr[n] = es + pref[t];
    }
    if (b == NB - 1 && t == 0) rowptr[N] = ee;
    __syncthreads();
    for (int i = es + t; i < ee; i += 256) {
        unsigned p = ep[i];
        int pos = es + atomicAdd(&pref[(p >> 20) & 127], 1);
        csr[pos] = (int)(p & 0xFFFFFu);
    }
}

__global__ void k_lin0(const float* __restrict__ x, const float* __restrict__ W0,
                       const float* __restrict__ b0, float* __restrict__ h, int N) {
    __shared__ __align__(16) float Ws[DIN * 52];
    __shared__ float pb[52];
    int t = threadIdx.x;
    for (int i = t; i < DIN * 52; i += 256) {
        int k = i / 52, c = i - k * 52;
        Ws[i] = (c < DV) ? W0[k * DV + c] : 0.f;
    }
    for (int i = t; i < 52; i += 256) pb[i] = (i < DV) ? b0[i] : 0.f;
    __syncthreads();
    int n = blockIdx.x * 256 + t;
    if (n >= N) return;
    float row[DIN];
    const float* xr = x + (size_t)n * DIN;
#pragma unroll
    for (int q = 0; q < DIN / 4; q++) {
        float4 v = *(const float4*)&xr[q * 4];
        row[q * 4 + 0] = v.x; row[q * 4 + 1] = v.y;
        row[q * 4 + 2] = v.z; row[q * 4 + 3] = v.w;
    }
    float acc[52];
#pragma unroll
    for (int c = 0; c < 52; c++) acc[c] = pb[c];
    for (int k = 0; k < DIN; k++) {
        float xv = row[k];
#pragma unroll
        for (int c4 = 0; c4 < 13; c4++) {
            float4 w = *(const float4*)&Ws[k * 52 + c4 * 4];
            acc[c4 * 4 + 0] = fmaf(xv, w.x, acc[c4 * 4 + 0]);
            acc[c4 * 4 + 1] = fmaf(xv, w.y, acc[c4 * 4 + 1]);
            acc[c4 * 4 + 2] = fmaf(xv, w.z, acc[c4 * 4 + 2]);
            acc[c4 * 4 + 3] = fmaf(xv, w.w, acc[c4 * 4 + 3]);
        }
    }
    float* hr = h + (size_t)n * LD;
#pragma unroll
    for (int c4 = 0; c4 < 13; c4++) {
        float4 o;
        o.x = acc[c4 * 4 + 0]; o.y = acc[c4 * 4 + 1];
        o.z = acc[c4 * 4 + 2]; o.w = acc[c4 * 4 + 3];
        *(float4*)&hr[c4 * 4] = o;
    }
    float4 zz = make_float4(0.f, 0.f, 0.f, 0.f);
    *(float4*)&hr[52] = zz;
    *(float4*)&hr[56] = zz;
    *(float4*)&hr[60] = zz;
}

// One wave per node; lane = padded column; register accumulate; no LDS.
// BN+ReLU of the previous layer folded into the gather (and the self term).
template <bool BN_IN>
__global__ void k_agg(const float* __restrict__ hin, float* __restrict__ zout,
                      const int* __restrict__ rowptr, const int* __restrict__ csr,
                      const float* __restrict__ gam, const float* __restrict__ bet,
                      const float* __restrict__ stats, float invN,
                      const float* __restrict__ eps_gin, int l, int N) {
    int wave = threadIdx.x >> 6;
    int lane = threadIdx.x & 63;
    int n = blockIdx.x * 4 + wave;
    if (n >= N) return;
    float scr = 1.f, shr = 0.f;
    if (BN_IN) {
        if (lane < DV) {
            float mu = stats[lane] * invN;
            float var = stats[64 + lane] * invN - mu * mu;
            float s = gam[lane] * rsqrtf(var + 1e-5f);
            scr = s;
            shr = bet[lane] - mu * s;
        } else {
            scr = 0.f;
            shr = 0.f;
        }
    }
    int s = rowptr[n], e = rowptr[n + 1];
    float acc = 0.f;
    int deg = e - s;
    for (int base = 0; base < deg; base += 64) {
        int m = min(64, deg - base);
        int sv = (lane < m) ? csr[s + base + lane] : 0;
        int i = 0;
        for (; i + 8 <= m; i += 8) {
            int s0 = __shfl(sv, i), s1 = __shfl(sv, i + 1);
            int s2 = __shfl(sv, i + 2), s3 = __shfl(sv, i + 3);
            int s4 = __shfl(sv, i + 4), s5 = __shfl(sv, i + 5);
            int s6 = __shfl(sv, i + 6), s7 = __shfl(sv, i + 7);
            float v0 = hin[(size_t)s0 * LD + lane];
            float v1 = hin[(size_t)s1 * LD + lane];
            float v2 = hin[(size_t)s2 * LD + lane];
            float v3 = hin[(size_t)s3 * LD + lane];
            float v4 = hin[(size_t)s4 * LD + lane];
            float v5 = hin[(size_t)s5 * LD + lane];
            float v6 = hin[(size_t)s6 * LD + lane];
            float v7 = hin[(size_t)s7 * LD + lane];
            if (BN_IN) {
                v0 = fmaxf(0.f, fmaf(v0, scr, shr));
                v1 = fmaxf(0.f, fmaf(v1, scr, shr));
                v2 = fmaxf(0.f, fmaf(v2, scr, shr));
                v3 = fmaxf(0.f, fmaf(v3, scr, shr));
                v4 = fmaxf(0.f, fmaf(v4, scr, shr));
                v5 = fmaxf(0.f, fmaf(v5, scr, shr));
                v6 = fmaxf(0.f, fmaf(v6, scr, shr));
                v7 = fmaxf(0.f, fmaf(v7, scr, shr));
            }
            acc += v0 + v1 + v2 + v3 + v4 + v5 + v6 + v7;
        }
        for (; i < m; i++) {
            int sidx = __shfl(sv, i);
            float v = hin[(size_t)sidx * LD + lane];
            if (BN_IN) v = fmaxf(0.f, fmaf(v, scr, shr));
            acc += v;
        }
    }
    float eps1 = 1.f + eps_gin[l];
    float self = hin[(size_t)n * LD + lane];
    if (BN_IN) self = fmaxf(0.f, fmaf(self, scr, shr));
    zout[(size_t)n * LD + lane] = acc + eps1 * self;
}

// One thread per row; input row preloaded to registers (13x float4). Optional BN+ReLU of
// the input (stats of the previous linear); column sum/sumsq of output for the next BN.
template <bool BN_IN>
__global__ void k_gemm(const float* in, float* out,
                       const float* __restrict__ W, const float* __restrict__ bias,
                       const float* __restrict__ gam, const float* __restrict__ bet,
                       const float* __restrict__ statsIn, float* __restrict__ statsOut,
                       float invN, int N) {
    __shared__ __align__(16) float Ws[DV * 52];
    __shared__ float pb[52];
    __shared__ float sc[DV], sh[DV];
    int t = threadIdx.x;
    for (int i = t; i < DV * 52; i += 256) {
        int k = i / 52, c = i - k * 52;
        Ws[i] = (c < DV) ? W[k * DV + c] : 0.f;
    }
    for (int i = t; i < 52; i += 256) pb[i] = (i < DV) ? bias[i] : 0.f;
    if (BN_IN) {
        if (t < DV) {
            float mu = statsIn[t] * invN;
            float var = statsIn[64 + t] * invN - mu * mu;
            float s = gam[t] * rsqrtf(var + 1e-5f);
            sc[t] = s;
            sh[t] = bet[t] - mu * s;
        }
    }
    __syncthreads();
    int n = blockIdx.x * 256 + t;
    bool active = (n < N);
    float row[52];
    if (active) {
        const float* rp = in + (size_t)n * LD;
#pragma unroll
        for (int q = 0; q < 13; q++) {
            float4 v = *(const float4*)&rp[q * 4];
            row[q * 4 + 0] = v.x; row[q * 4 + 1] = v.y;
            row[q * 4 + 2] = v.z; row[q * 4 + 3] = v.w;
        }
        if (BN_IN) {
#pragma unroll
            for (int k = 0; k < DV; k++) row[k] = fmaxf(0.f, fmaf(row[k], sc[k], sh[k]));
        }
    } else {
#pragma unroll
        for (int q = 0; q < 52; q++) row[q] = 0.f;
    }
    float acc[52];
#pragma unroll
    for (int c = 0; c < 52; c++) acc[c] = pb[c];
    for (int k = 0; k < DV; k++) {
        float xv = row[k];
#pragma unroll
        for (int c4 = 0; c4 < 13; c4++) {
            float4 w = *(const float4*)&Ws[k * 52 + c4 * 4];
            acc[c4 * 4 + 0] = fmaf(xv, w.x, acc[c4 * 4 + 0]);
            acc[c4 * 4 + 1] = fmaf(xv, w.y, acc[c4 * 4 + 1]);
            acc[c4 * 4 + 2] = fmaf(xv, w.z, acc[c4 * 4 + 2]);
            acc[c4 * 4 + 3] = fmaf(xv, w.w, acc[c4 * 4 + 3]);
        }
    }
    if (active) {
        float* orow = out + (size_t)n * LD;
#pragma unroll
        for (int c4 = 0; c4 < 13; c4++) {
            float4 o;
            o.x = acc[c4 * 4 + 0]; o.y = acc[c4 * 4 + 1];
            o.z = acc[c4 * 4 + 2]; o.w = acc[c4 * 4 + 3];
            *(float4*)&orow[c4 * 4] = o;
        }
        float4 zz = make_float4(0.f, 0.f, 0.f, 0.f);
        *(float4*)&orow[52] = zz;
        *(float4*)&orow[56] = zz;
        *(float4*)&orow[60] = zz;
    }
    // wave butterfly per column; lane c keeps column c's totals; 2 atomics/wave.
    float myS = 0.f, myQ = 0.f;
    int lane = t & 63;
#pragma unroll
    for (int c = 0; c < DV; c++) {
        float v = active ? acc[c] : 0.f;
        float s = v, q = v * v;
#pragma unroll
        for (int off = 32; off > 0; off >>= 1) {
            s += __shfl_xor(s, off);
            q += __shfl_xor(q, off);
        }
        if (lane == c) { myS = s; myQ = q; }
    }
    if (lane < DV) {
        atomicAdd(&statsOut[lane], myS);
        atomicAdd(&statsOut[64 + lane], myQ);
    }
}

// batch sorted: one wave per graph, binary search range, fold final BN+ReLU.
__global__ void k_pool(const float* __restrict__ h, const int* __restrict__ batch,
                       const float* __restrict__ gam, const float* __restrict__ bet,
                       const float* __restrict__ stats, float invN,
                       float* __restrict__ out, int N) {
    int g = blockIdx.x;
    int lane = threadIdx.x;
    int lo, hi;
    {
        int a = 0, b = N;
        while (a < b) { int mid = (a + b) >> 1; if (batch[mid] < g) a = mid + 1; else b = mid; }
        lo = a;
    }
    {
        int a = lo, b = N;
        while (a < b) { int mid = (a + b) >> 1; if (batch[mid] < g + 1) a = mid + 1; else b = mid; }
        hi = a;
    }
    float scv = 0.f, shv = 0.f;
    if (lane < DV) {
        float mu = stats[lane] * invN;
        float var = stats[64 + lane] * invN - mu * mu;
        float s = gam[lane] * rsqrtf(var + 1e-5f);
        scv = s;
        shv = bet[lane] - mu * s;
    }
    float a0 = 0.f, a1 = 0.f, a2 = 0.f, a3 = 0.f;
    int n2 = lo;
    for (; n2 + 4 <= hi; n2 += 4) {
        a0 += fmaxf(0.f, fmaf(h[(size_t)(n2 + 0) * LD + lane], scv, shv));
        a1 += fmaxf(0.f, fmaf(h[(size_t)(n2 + 1) * LD + lane], scv, shv));
        a2 += fmaxf(0.f, fmaf(h[(size_t)(n2 + 2) * LD + lane], scv, shv));
        a3 += fmaxf(0.f, fmaf(h[(size_t)(n2 + 3) * LD + lane], scv, shv));
    }
    for (; n2 < hi; n2++)
        a0 += fmaxf(0.f, fmaf(h[(size_t)n2 * LD + lane], scv, shv));
    float acc = (a0 + a1) + (a2 + a3);
    float cnt = (float)max(hi - lo, 1);
    if (lane < DV) out[g * DV + lane] = acc / cnt;
}

extern "C" void kernel_launch(void* const* d_in, const int* in_sizes, int n_in,
                              void* d_out, int out_size, void* d_ws, size_t ws_size,
                              hipStream_t stream) {
    const float* x = (const float*)d_in[0];
    const float* W0 = (const float*)d_in[1];
    const float* b0 = (const float*)d_in[2];
    const float* W1 = (const float*)d_in[3];
    const float* b1 = (const float*)d_in[4];
    const float* g1 = (const float*)d_in[5];
    const float* be1 = (const float*)d_in[6];
    const float* W2 = (const float*)d_in[7];
    const float* b2 = (const float*)d_in[8];
    const float* g2 = (const float*)d_in[9];
    const float* be2 = (const float*)d_in[10];
    const float* eps_gin = (const float*)d_in[11];
    const int* edge_index = (const int*)d_in[12];
    const int* batch = (const int*)d_in[13];
    float* out = (float*)d_out;

    int N = in_sizes[0] / DIN;
    int E = in_sizes[12] / 2;
    const int* esrc = edge_index;
    const int* edst = edge_index + E;
    int NB = (N + BSZ - 1) >> BSH;

    char* ws = (char*)d_ws;
    size_t off = 0;
    auto alloc = [&](size_t bytes) -> void* {
        void* p = ws + off;
        off = (off + bytes + 255) & ~(size_t)255;
        return p;
    };
    float* P = (float*)alloc((size_t)N * LD * 4);   // activations (ping)
    float* A = (float*)alloc((size_t)N * LD * 4);   // activations (pong)
    unsigned int* ep = (unsigned int*)alloc((size_t)E * 4);
    int* csr = (int*)alloc((size_t)E * 4);
    int* rowptr = (int*)alloc((size_t)(N + 1) * 4);
    int* ghist = (int*)alloc((size_t)NB * 4);
    int* bstart = (int*)alloc((size_t)(NB + 1) * 4);
    int* cursor = (int*)alloc((size_t)NB * 4);
    float* stats = (float*)alloc(NLAY * 2 * 128 * 4);
    (void)ws_size;  // needs ~65 MB

    float invN = 1.f / (float)N;
    int gN = (N + 255) / 256;

    k_zero<<<8, 256, 0, stream>>>(ghist, NB, stats);
    k_hist_b<<<1024, 256, 0, stream>>>(edst, E, ghist, NB);
    k_scanb<<<1, 256, 0, stream>>>(ghist, NB, bstart, cursor);
    k_scatter_b<<<256, 256, 0, stream>>>(esrc, edst, E, cursor, ep, NB);
    k_sortb<<<NB, 256, 0, stream>>>(ep, bstart, csr, rowptr, N, NB);
    k_lin0<<<gN, 256, 0, stream>>>(x, W0, b0, P, N);

    for (int l = 0; l < NLAY; l++) {
        float* S1 = stats + (l * 2 + 0) * 128;
        float* S2 = stats + (l * 2 + 1) * 128;
        if (l == 0) {
            k_agg<false><<<(N + 3) / 4, 256, 0, stream>>>(P, A, rowptr, csr, nullptr,
                                                          nullptr, nullptr, invN,
                                                          eps_gin, l, N);
        } else {
            float* S2p = stats + ((l - 1) * 2 + 1) * 128;
            k_agg<true><<<(N + 3) / 4, 256, 0, stream>>>(P, A, rowptr, csr,
                                                         g2 + (l - 1) * DV,
                                                         be2 + (l - 1) * DV, S2p, invN,
                                                         eps_gin, l, N);
        }
        k_gemm<false><<<gN, 256, 0, stream>>>(A, A, W1 + (size_t)l * DV * DV, b1 + l * DV,
                                              nullptr, nullptr, nullptr, S1, invN, N);
        k_gemm<true><<<gN, 256, 0, stream>>>(A, P, W2 + (size_t)l * DV * DV, b2 + l * DV,
                                             g1 + l * DV, be1 + l * DV, S1, S2, invN, N);
    }
    float* S2last = stats + ((NLAY - 1) * 2 + 1) * 128;
    k_pool<<<NGR, 64, 0, stream>>>(P, batch, g2 + (NLAY - 1) * DV, be2 + (NLAY - 1) * DV,
                                   S2last, invN, out, N);
}

// Round 6
// 862.786 us; speedup vs baseline: 3.2737x; 1.0781x over previous
//
#include <hip/hip_runtime.h>

// GIN forward. lin0 -> 3x [GINConv(sum-agg) -> Lin->BN->ReLU->Lin->BN->ReLU] -> mean-pool
// N=100000, E=1.6M, D=49 (pad LD=64), NG=512.
//
// Round-6: ONE change vs round 5. rocprof showed k_gemm at VGPR_Count=64 while
// holding row[52]+acc[52] live -> compiler spilled to scratch (WRITE_SIZE 77MB vs
// 25.6MB real output; VALUBusy 5.6%; 114us/dispatch vs ~10us roofline).
// Fix: __launch_bounds__(256, 2) on k_gemm and k_lin0 (256-VGPR budget, no spill).
// Everything else identical to the passing round-5 kernel.

#define DV 49
#define LD 64
#define DIN 56
#define NGR 512
#define NLAY 3
#define BSH 7
#define BSZ 128
#define MAXNB 1024  // supports N <= 131072

__global__ void k_zero(int* __restrict__ ghist, int NB, float* __restrict__ stats) {
    int i = blockIdx.x * blockDim.x + threadIdx.x;
    int stride = gridDim.x * blockDim.x;
    for (int j = i; j < NB; j += stride) ghist[j] = 0;
    for (int j = i; j < NLAY * 2 * 128; j += stride) stats[j] = 0.f;
}

__global__ void k_hist_b(const int* __restrict__ dst, int E, int* __restrict__ ghist, int NB) {
    __shared__ int lh[MAXNB];
    int t = threadIdx.x;
    for (int i = t; i < NB; i += 256) lh[i] = 0;
    __syncthreads();
    int chunk = (E + gridDim.x - 1) / gridDim.x;
    int s = blockIdx.x * chunk, e = min(E, s + chunk);
    for (int i = s + t; i < e; i += 256) atomicAdd(&lh[dst[i] >> BSH], 1);
    __syncthreads();
    for (int i = t; i < NB; i += 256)
        if (lh[i]) atomicAdd(&ghist[i], lh[i]);
}

__global__ void k_scanb(const int* __restrict__ g, int NB, int* __restrict__ bstart,
                        int* __restrict__ cursor) {
    __shared__ int sm[256];
    __shared__ int carry;
    int t = threadIdx.x;
    if (t == 0) carry = 0;
    __syncthreads();
    for (int base = 0; base < NB; base += 256) {
        int v = (base + t < NB) ? g[base + t] : 0;
        sm[t] = v;
        __syncthreads();
        for (int off = 1; off < 256; off <<= 1) {
            int x = (t >= off) ? sm[t - off] : 0;
            __syncthreads();
            sm[t] += x;
            __syncthreads();
        }
        int excl = sm[t] - v + carry;
        if (base + t < NB) { bstart[base + t] = excl; cursor[base + t] = excl; }
        int tot = sm[255];
        __syncthreads();
        if (t == 0) carry += tot;
        __syncthreads();
    }
    if (t == 0) bstart[NB] = carry;
}

__global__ void k_scatter_b(const int* __restrict__ src, const int* __restrict__ dst, int E,
                            int* __restrict__ cursor, unsigned int* __restrict__ ep, int NB) {
    __shared__ int lcount[MAXNB];
    __shared__ int lbase[MAXNB];
    __shared__ int lofs[MAXNB];
    int t = threadIdx.x;
    for (int i = t; i < NB; i += 256) { lcount[i] = 0; lofs[i] = 0; }
    __syncthreads();
    int chunk = (E + gridDim.x - 1) / gridDim.x;
    int s = blockIdx.x * chunk, e = min(E, s + chunk);
    for (int i = s + t; i < e; i += 256) atomicAdd(&lcount[dst[i] >> BSH], 1);
    __syncthreads();
    for (int i = t; i < NB; i += 256)
        if (lcount[i]) lbase[i] = atomicAdd(&cursor[i], lcount[i]);
    __syncthreads();
    for (int i = s + t; i < e; i += 256) {
        int d = dst[i];
        int b = d >> BSH;
        int pos = lbase[b] + atomicAdd(&lofs[b], 1);
        ep[pos] = (unsigned)src[i] | ((unsigned)(d & (BSZ - 1)) << 20);
    }
}

// One block per bucket: counting-sort packed records by dstLocal -> per-node CSR + rowptr.
__global__ void k_sortb(const unsigned int* __restrict__ ep, const int* __restrict__ bstart,
                        int* __restrict__ csr, int* __restrict__ rowptr, int N, int NB) {
    __shared__ int cnt[BSZ];
    __shared__ int pref[BSZ];
    int t = threadIdx.x;
    int b = blockIdx.x;
    int es = bstart[b], ee = bstart[b + 1];
    if (t < BSZ) cnt[t] = 0;
    __syncthreads();
    for (int i = es + t; i < ee; i += 256) atomicAdd(&cnt[(ep[i] >> 20) & 127], 1);
    __syncthreads();
    if (t < BSZ) pref[t] = cnt[t];
    __syncthreads();
    for (int off = 1; off < BSZ; off <<= 1) {
        int x = 0;
        if (t < BSZ && t >= off) x = pref[t - off];
        __syncthreads();
        if (t < BSZ && t >= off) pref[t] += x;
        __syncthreads();
    }
    // exclusive prefix
    if (t < BSZ) pref[t] -= cnt[t];
    __syncthreads();
    if (t < BSZ) {
        int n = (b << BSH) + t;
        if (n < N) rowptr[n] = es + pref[t];
    }
    if (b == NB - 1 && t == 0) rowptr[N] = ee;
    __syncthreads();
    for (int i = es + t; i < ee; i += 256) {
        unsigned p = ep[i];
        int pos = es + atomicAdd(&pref[(p >> 20) & 127], 1);
        csr[pos] = (int)(p & 0xFFFFFu);
    }
}

__global__ __launch_bounds__(256, 2)
void k_lin0(const float* __restrict__ x, const float* __restrict__ W0,
            const float* __restrict__ b0, float* __restrict__ h, int N) {
    __shared__ __align__(16) float Ws[DIN * 52];
    __shared__ float pb[52];
    int t = threadIdx.x;
    for (int i = t; i < DIN * 52; i += 256) {
        int k = i / 52, c = i - k * 52;
        Ws[i] = (c < DV) ? W0[k * DV + c] : 0.f;
    }
    for (int i = t; i < 52; i += 256) pb[i] = (i < DV) ? b0[i] : 0.f;
    __syncthreads();
    int n = blockIdx.x * 256 + t;
    if (n >= N) return;
    float row[DIN];
    const float* xr = x + (size_t)n * DIN;
#pragma unroll
    for (int q = 0; q < DIN / 4; q++) {
        float4 v = *(const float4*)&xr[q * 4];
        row[q * 4 + 0] = v.x; row[q * 4 + 1] = v.y;
        row[q * 4 + 2] = v.z; row[q * 4 + 3] = v.w;
    }
    float acc[52];
#pragma unroll
    for (int c = 0; c < 52; c++) acc[c] = pb[c];
    for (int k = 0; k < DIN; k++) {
        float xv = row[k];
#pragma unroll
        for (int c4 = 0; c4 < 13; c4++) {
            float4 w = *(const float4*)&Ws[k * 52 + c4 * 4];
            acc[c4 * 4 + 0] = fmaf(xv, w.x, acc[c4 * 4 + 0]);
            acc[c4 * 4 + 1] = fmaf(xv, w.y, acc[c4 * 4 + 1]);
            acc[c4 * 4 + 2] = fmaf(xv, w.z, acc[c4 * 4 + 2]);
            acc[c4 * 4 + 3] = fmaf(xv, w.w, acc[c4 * 4 + 3]);
        }
    }
    float* hr = h + (size_t)n * LD;
#pragma unroll
    for (int c4 = 0; c4 < 13; c4++) {
        float4 o;
        o.x = acc[c4 * 4 + 0]; o.y = acc[c4 * 4 + 1];
        o.z = acc[c4 * 4 + 2]; o.w = acc[c4 * 4 + 3];
        *(float4*)&hr[c4 * 4] = o;
    }
    float4 zz = make_float4(0.f, 0.f, 0.f, 0.f);
    *(float4*)&hr[52] = zz;
    *(float4*)&hr[56] = zz;
    *(float4*)&hr[60] = zz;
}

// One wave per node; lane = padded column; register accumulate; no LDS.
// BN+ReLU of the previous layer folded into the gather (and the self term).
template <bool BN_IN>
__global__ void k_agg(const float* __restrict__ hin, float* __restrict__ zout,
                      const int* __restrict__ rowptr, const int* __restrict__ csr,
                      const float* __restrict__ gam, const float* __restrict__ bet,
                      const float* __restrict__ stats, float invN,
                      const float* __restrict__ eps_gin, int l, int N) {
    int wave = threadIdx.x >> 6;
    int lane = threadIdx.x & 63;
    int n = blockIdx.x * 4 + wave;
    if (n >= N) return;
    float scr = 1.f, shr = 0.f;
    if (BN_IN) {
        if (lane < DV) {
            float mu = stats[lane] * invN;
            float var = stats[64 + lane] * invN - mu * mu;
            float s = gam[lane] * rsqrtf(var + 1e-5f);
            scr = s;
            shr = bet[lane] - mu * s;
        } else {
            scr = 0.f;
            shr = 0.f;
        }
    }
    int s = rowptr[n], e = rowptr[n + 1];
    float acc = 0.f;
    int deg = e - s;
    for (int base = 0; base < deg; base += 64) {
        int m = min(64, deg - base);
        int sv = (lane < m) ? csr[s + base + lane] : 0;
        int i = 0;
        for (; i + 8 <= m; i += 8) {
            int s0 = __shfl(sv, i), s1 = __shfl(sv, i + 1);
            int s2 = __shfl(sv, i + 2), s3 = __shfl(sv, i + 3);
            int s4 = __shfl(sv, i + 4), s5 = __shfl(sv, i + 5);
            int s6 = __shfl(sv, i + 6), s7 = __shfl(sv, i + 7);
            float v0 = hin[(size_t)s0 * LD + lane];
            float v1 = hin[(size_t)s1 * LD + lane];
            float v2 = hin[(size_t)s2 * LD + lane];
            float v3 = hin[(size_t)s3 * LD + lane];
            float v4 = hin[(size_t)s4 * LD + lane];
            float v5 = hin[(size_t)s5 * LD + lane];
            float v6 = hin[(size_t)s6 * LD + lane];
            float v7 = hin[(size_t)s7 * LD + lane];
            if (BN_IN) {
                v0 = fmaxf(0.f, fmaf(v0, scr, shr));
                v1 = fmaxf(0.f, fmaf(v1, scr, shr));
                v2 = fmaxf(0.f, fmaf(v2, scr, shr));
                v3 = fmaxf(0.f, fmaf(v3, scr, shr));
                v4 = fmaxf(0.f, fmaf(v4, scr, shr));
                v5 = fmaxf(0.f, fmaf(v5, scr, shr));
                v6 = fmaxf(0.f, fmaf(v6, scr, shr));
                v7 = fmaxf(0.f, fmaf(v7, scr, shr));
            }
            acc += v0 + v1 + v2 + v3 + v4 + v5 + v6 + v7;
        }
        for (; i < m; i++) {
            int sidx = __shfl(sv, i);
            float v = hin[(size_t)sidx * LD + lane];
            if (BN_IN) v = fmaxf(0.f, fmaf(v, scr, shr));
            acc += v;
        }
    }
    float eps1 = 1.f + eps_gin[l];
    float self = hin[(size_t)n * LD + lane];
    if (BN_IN) self = fmaxf(0.f, fmaf(self, scr, shr));
    zout[(size_t)n * LD + lane] = acc + eps1 * self;
}

// One thread per row; input row preloaded to registers (13x float4). Optional BN+ReLU of
// the input (stats of the previous linear); column sum/sumsq of output for the next BN.
template <bool BN_IN>
__global__ __launch_bounds__(256, 2)
void k_gemm(const float* in, float* out,
            const float* __restrict__ W, const float* __restrict__ bias,
            const float* __restrict__ gam, const float* __restrict__ bet,
            const float* __restrict__ statsIn, float* __restrict__ statsOut,
            float invN, int N) {
    __shared__ __align__(16) float Ws[DV * 52];
    __shared__ float pb[52];
    __shared__ float sc[DV], sh[DV];
    int t = threadIdx.x;
    for (int i = t; i < DV * 52; i += 256) {
        int k = i / 52, c = i - k * 52;
        Ws[i] = (c < DV) ? W[k * DV + c] : 0.f;
    }
    for (int i = t; i < 52; i += 256) pb[i] = (i < DV) ? bias[i] : 0.f;
    if (BN_IN) {
        if (t < DV) {
            float mu = statsIn[t] * invN;
            float var = statsIn[64 + t] * invN - mu * mu;
            float s = gam[t] * rsqrtf(var + 1e-5f);
            sc[t] = s;
            sh[t] = bet[t] - mu * s;
        }
    }
    __syncthreads();
    int n = blockIdx.x * 256 + t;
    bool active = (n < N);
    float row[52];
    if (active) {
        const float* rp = in + (size_t)n * LD;
#pragma unroll
        for (int q = 0; q < 13; q++) {
            float4 v = *(const float4*)&rp[q * 4];
            row[q * 4 + 0] = v.x; row[q * 4 + 1] = v.y;
            row[q * 4 + 2] = v.z; row[q * 4 + 3] = v.w;
        }
        if (BN_IN) {
#pragma unroll
            for (int k = 0; k < DV; k++) row[k] = fmaxf(0.f, fmaf(row[k], sc[k], sh[k]));
        }
    } else {
#pragma unroll
        for (int q = 0; q < 52; q++) row[q] = 0.f;
    }
    float acc[52];
#pragma unroll
    for (int c = 0; c < 52; c++) acc[c] = pb[c];
    for (int k = 0; k < DV; k++) {
        float xv = row[k];
#pragma unroll
        for (int c4 = 0; c4 < 13; c4++) {
            float4 w = *(const float4*)&Ws[k * 52 + c4 * 4];
            acc[c4 * 4 + 0] = fmaf(xv, w.x, acc[c4 * 4 + 0]);
            acc[c4 * 4 + 1] = fmaf(xv, w.y, acc[c4 * 4 + 1]);
            acc[c4 * 4 + 2] = fmaf(xv, w.z, acc[c4 * 4 + 2]);
            acc[c4 * 4 + 3] = fmaf(xv, w.w, acc[c4 * 4 + 3]);
        }
    }
    if (active) {
        float* orow = out + (size_t)n * LD;
#pragma unroll
        for (int c4 = 0; c4 < 13; c4++) {
            float4 o;
            o.x = acc[c4 * 4 + 0]; o.y = acc[c4 * 4 + 1];
            o.z = acc[c4 * 4 + 2]; o.w = acc[c4 * 4 + 3];
            *(float4*)&orow[c4 * 4] = o;
        }
        float4 zz = make_float4(0.f, 0.f, 0.f, 0.f);
        *(float4*)&orow[52] = zz;
        *(float4*)&orow[56] = zz;
        *(float4*)&orow[60] = zz;
    }
    // wave butterfly per column; lane c keeps column c's totals; 2 atomics/wave.
    float myS = 0.f, myQ = 0.f;
    int lane = t & 63;
#pragma unroll
    for (int c = 0; c < DV; c++) {
        float v = active ? acc[c] : 0.f;
        float s = v, q = v * v;
#pragma unroll
        for (int off = 32; off > 0; off >>= 1) {
            s += __shfl_xor(s, off);
            q += __shfl_xor(q, off);
        }
        if (lane == c) { myS = s; myQ = q; }
    }
    if (lane < DV) {
        atomicAdd(&statsOut[lane], myS);
        atomicAdd(&statsOut[64 + lane], myQ);
    }
}

// batch sorted: one wave per graph, binary search range, fold final BN+ReLU.
__global__ void k_pool(const float* __restrict__ h, const int* __restrict__ batch,
                       const float* __restrict__ gam, const float* __restrict__ bet,
                       const float* __restrict__ stats, float invN,
                       float* __restrict__ out, int N) {
    int g = blockIdx.x;
    int lane = threadIdx.x;
    int lo, hi;
    {
        int a = 0, b = N;
        while (a < b) { int mid = (a + b) >> 1; if (batch[mid] < g) a = mid + 1; else b = mid; }
        lo = a;
    }
    {
        int a = lo, b = N;
        while (a < b) { int mid = (a + b) >> 1; if (batch[mid] < g + 1) a = mid + 1; else b = mid; }
        hi = a;
    }
    float scv = 0.f, shv = 0.f;
    if (lane < DV) {
        float mu = stats[lane] * invN;
        float var = stats[64 + lane] * invN - mu * mu;
        float s = gam[lane] * rsqrtf(var + 1e-5f);
        scv = s;
        shv = bet[lane] - mu * s;
    }
    float a0 = 0.f, a1 = 0.f, a2 = 0.f, a3 = 0.f;
    int n2 = lo;
    for (; n2 + 4 <= hi; n2 += 4) {
        a0 += fmaxf(0.f, fmaf(h[(size_t)(n2 + 0) * LD + lane], scv, shv));
        a1 += fmaxf(0.f, fmaf(h[(size_t)(n2 + 1) * LD + lane], scv, shv));
        a2 += fmaxf(0.f, fmaf(h[(size_t)(n2 + 2) * LD + lane], scv, shv));
        a3 += fmaxf(0.f, fmaf(h[(size_t)(n2 + 3) * LD + lane], scv, shv));
    }
    for (; n2 < hi; n2++)
        a0 += fmaxf(0.f, fmaf(h[(size_t)n2 * LD + lane], scv, shv));
    float acc = (a0 + a1) + (a2 + a3);
    float cnt = (float)max(hi - lo, 1);
    if (lane < DV) out[g * DV + lane] = acc / cnt;
}

extern "C" void kernel_launch(void* const* d_in, const int* in_sizes, int n_in,
                              void* d_out, int out_size, void* d_ws, size_t ws_size,
                              hipStream_t stream) {
    const float* x = (const float*)d_in[0];
    const float* W0 = (const float*)d_in[1];
    const float* b0 = (const float*)d_in[2];
    const float* W1 = (const float*)d_in[3];
    const float* b1 = (const float*)d_in[4];
    const float* g1 = (const float*)d_in[5];
    const float* be1 = (const float*)d_in[6];
    const float* W2 = (const float*)d_in[7];
    const float* b2 = (const float*)d_in[8];
    const float* g2 = (const float*)d_in[9];
    const float* be2 = (const float*)d_in[10];
    const float* eps_gin = (const float*)d_in[11];
    const int* edge_index = (const int*)d_in[12];
    const int* batch = (const int*)d_in[13];
    float* out = (float*)d_out;

    int N = in_sizes[0] / DIN;
    int E = in_sizes[12] / 2;
    const int* esrc = edge_index;
    const int* edst = edge_index + E;
    int NB = (N + BSZ - 1) >> BSH;

    char* ws = (char*)d_ws;
    size_t off = 0;
    auto alloc = [&](size_t bytes) -> void* {
        void* p = ws + off;
        off = (off + bytes + 255) & ~(size_t)255;
        return p;
    };
    float* P = (float*)alloc((size_t)N * LD * 4);   // activations (ping)
    float* A = (float*)alloc((size_t)N * LD * 4);   // activations (pong)
    unsigned int* ep = (unsigned int*)alloc((size_t)E * 4);
    int* csr = (int*)alloc((size_t)E * 4);
    int* rowptr = (int*)alloc((size_t)(N + 1) * 4);
    int* ghist = (int*)alloc((size_t)NB * 4);
    int* bstart = (int*)alloc((size_t)(NB + 1) * 4);
    int* cursor = (int*)alloc((size_t)NB * 4);
    float* stats = (float*)alloc(NLAY * 2 * 128 * 4);
    (void)ws_size;  // needs ~65 MB

    float invN = 1.f / (float)N;
    int gN = (N + 255) / 256;

    k_zero<<<8, 256, 0, stream>>>(ghist, NB, stats);
    k_hist_b<<<1024, 256, 0, stream>>>(edst, E, ghist, NB);
    k_scanb<<<1, 256, 0, stream>>>(ghist, NB, bstart, cursor);
    k_scatter_b<<<256, 256, 0, stream>>>(esrc, edst, E, cursor, ep, NB);
    k_sortb<<<NB, 256, 0, stream>>>(ep, bstart, csr, rowptr, N, NB);
    k_lin0<<<gN, 256, 0, stream>>>(x, W0, b0, P, N);

    for (int l = 0; l < NLAY; l++) {
        float* S1 = stats + (l * 2 + 0) * 128;
        float* S2 = stats + (l * 2 + 1) * 128;
        if (l == 0) {
            k_agg<false><<<(N + 3) / 4, 256, 0, stream>>>(P, A, rowptr, csr, nullptr,
                                                          nullptr, nullptr, invN,
                                                          eps_gin, l, N);
        } else {
            float* S2p = stats + ((l - 1) * 2 + 1) * 128;
            k_agg<true><<<(N + 3) / 4, 256, 0, stream>>>(P, A, rowptr, csr,
                                                         g2 + (l - 1) * DV,
                                                         be2 + (l - 1) * DV, S2p, invN,
                                                         eps_gin, l, N);
        }
        k_gemm<false><<<gN, 256, 0, stream>>>(A, A, W1 + (size_t)l * DV * DV, b1 + l * DV,
                                              nullptr, nullptr, nullptr, S1, invN, N);
        k_gemm<true><<<gN, 256, 0, stream>>>(A, P, W2 + (size_t)l * DV * DV, b2 + l * DV,
                                             g1 + l * DV, be1 + l * DV, S1, S2, invN, N);
    }
    float* S2last = stats + ((NLAY - 1) * 2 + 1) * 128;
    k_pool<<<NGR, 64, 0, stream>>>(P, batch, g2 + (NLAY - 1) * DV, be2 + (NLAY - 1) * DV,
                                   S2last, invN, out, N);
}

// Round 7
// 844.038 us; speedup vs baseline: 3.3464x; 1.0222x over previous
//
#include <hip/hip_runtime.h>

// GIN forward. lin0 -> 3x [GINConv(sum-agg) -> Lin->BN->ReLU->Lin->BN->ReLU] -> mean-pool
// N=100000, E=1.6M, D=49 (pad LD=64), NG=512.
//
// Round-7: ONE change vs round 6. Round-6 still spilled row[52] to scratch
// (WRITE_SIZE 48MB vs 25.6MB real, VGPR=100 under a 256 budget): the K-loop
// `for (k) { xv = row[k]; }` indexes row[] with a RUNTIME k -> compiler puts the
// array in scratch (rule: runtime-indexed arrays never get registers).
// Fix: #pragma unroll on the K-loops of k_gemm (49 iters) and k_lin0 (56 iters)
// so every row[]/acc[] access is a compile-time-constant index.

#define DV 49
#define LD 64
#define DIN 56
#define NGR 512
#define NLAY 3
#define BSH 7
#define BSZ 128
#define MAXNB 1024  // supports N <= 131072

__global__ void k_zero(int* __restrict__ ghist, int NB, float* __restrict__ stats) {
    int i = blockIdx.x * blockDim.x + threadIdx.x;
    int stride = gridDim.x * blockDim.x;
    for (int j = i; j < NB; j += stride) ghist[j] = 0;
    for (int j = i; j < NLAY * 2 * 128; j += stride) stats[j] = 0.f;
}

__global__ void k_hist_b(const int* __restrict__ dst, int E, int* __restrict__ ghist, int NB) {
    __shared__ int lh[MAXNB];
    int t = threadIdx.x;
    for (int i = t; i < NB; i += 256) lh[i] = 0;
    __syncthreads();
    int chunk = (E + gridDim.x - 1) / gridDim.x;
    int s = blockIdx.x * chunk, e = min(E, s + chunk);
    for (int i = s + t; i < e; i += 256) atomicAdd(&lh[dst[i] >> BSH], 1);
    __syncthreads();
    for (int i = t; i < NB; i += 256)
        if (lh[i]) atomicAdd(&ghist[i], lh[i]);
}

__global__ void k_scanb(const int* __restrict__ g, int NB, int* __restrict__ bstart,
                        int* __restrict__ cursor) {
    __shared__ int sm[256];
    __shared__ int carry;
    int t = threadIdx.x;
    if (t == 0) carry = 0;
    __syncthreads();
    for (int base = 0; base < NB; base += 256) {
        int v = (base + t < NB) ? g[base + t] : 0;
        sm[t] = v;
        __syncthreads();
        for (int off = 1; off < 256; off <<= 1) {
            int x = (t >= off) ? sm[t - off] : 0;
            __syncthreads();
            sm[t] += x;
            __syncthreads();
        }
        int excl = sm[t] - v + carry;
        if (base + t < NB) { bstart[base + t] = excl; cursor[base + t] = excl; }
        int tot = sm[255];
        __syncthreads();
        if (t == 0) carry += tot;
        __syncthreads();
    }
    if (t == 0) bstart[NB] = carry;
}

__global__ void k_scatter_b(const int* __restrict__ src, const int* __restrict__ dst, int E,
                            int* __restrict__ cursor, unsigned int* __restrict__ ep, int NB) {
    __shared__ int lcount[MAXNB];
    __shared__ int lbase[MAXNB];
    __shared__ int lofs[MAXNB];
    int t = threadIdx.x;
    for (int i = t; i < NB; i += 256) { lcount[i] = 0; lofs[i] = 0; }
    __syncthreads();
    int chunk = (E + gridDim.x - 1) / gridDim.x;
    int s = blockIdx.x * chunk, e = min(E, s + chunk);
    for (int i = s + t; i < e; i += 256) atomicAdd(&lcount[dst[i] >> BSH], 1);
    __syncthreads();
    for (int i = t; i < NB; i += 256)
        if (lcount[i]) lbase[i] = atomicAdd(&cursor[i], lcount[i]);
    __syncthreads();
    for (int i = s + t; i < e; i += 256) {
        int d = dst[i];
        int b = d >> BSH;
        int pos = lbase[b] + atomicAdd(&lofs[b], 1);
        ep[pos] = (unsigned)src[i] | ((unsigned)(d & (BSZ - 1)) << 20);
    }
}

// One block per bucket: counting-sort packed records by dstLocal -> per-node CSR + rowptr.
__global__ void k_sortb(const unsigned int* __restrict__ ep, const int* __restrict__ bstart,
                        int* __restrict__ csr, int* __restrict__ rowptr, int N, int NB) {
    __shared__ int cnt[BSZ];
    __shared__ int pref[BSZ];
    int t = threadIdx.x;
    int b = blockIdx.x;
    int es = bstart[b], ee = bstart[b + 1];
    if (t < BSZ) cnt[t] = 0;
    __syncthreads();
    for (int i = es + t; i < ee; i += 256) atomicAdd(&cnt[(ep[i] >> 20) & 127], 1);
    __syncthreads();
    if (t < BSZ) pref[t] = cnt[t];
    __syncthreads();
    for (int off = 1; off < BSZ; off <<= 1) {
        int x = 0;
        if (t < BSZ && t >= off) x = pref[t - off];
        __syncthreads();
        if (t < BSZ && t >= off) pref[t] += x;
        __syncthreads();
    }
    // exclusive prefix
    if (t < BSZ) pref[t] -= cnt[t];
    __syncthreads();
    if (t < BSZ) {
        int n = (b << BSH) + t;
        if (n < N) rowptr[n] = es + pref[t];
    }
    if (b == NB - 1 && t == 0) rowptr[N] = ee;
    __syncthreads();
    for (int i = es + t; i < ee; i += 256) {
        unsigned p = ep[i];
        int pos = es + atomicAdd(&pref[(p >> 20) & 127], 1);
        csr[pos] = (int)(p & 0xFFFFFu);
    }
}

__global__ __launch_bounds__(256, 2)
void k_lin0(const float* __restrict__ x, const float* __restrict__ W0,
            const float* __restrict__ b0, float* __restrict__ h, int N) {
    __shared__ __align__(16) float Ws[DIN * 52];
    __shared__ float pb[52];
    int t = threadIdx.x;
    for (int i = t; i < DIN * 52; i += 256) {
        int k = i / 52, c = i - k * 52;
        Ws[i] = (c < DV) ? W0[k * DV + c] : 0.f;
    }
    for (int i = t; i < 52; i += 256) pb[i] = (i < DV) ? b0[i] : 0.f;
    __syncthreads();
    int n = blockIdx.x * 256 + t;
    if (n >= N) return;
    float row[DIN];
    const float* xr = x + (size_t)n * DIN;
#pragma unroll
    for (int q = 0; q < DIN / 4; q++) {
        float4 v = *(const float4*)&xr[q * 4];
        row[q * 4 + 0] = v.x; row[q * 4 + 1] = v.y;
        row[q * 4 + 2] = v.z; row[q * 4 + 3] = v.w;
    }
    float acc[52];
#pragma unroll
    for (int c = 0; c < 52; c++) acc[c] = pb[c];
#pragma unroll
    for (int k = 0; k < DIN; k++) {
        float xv = row[k];
#pragma unroll
        for (int c4 = 0; c4 < 13; c4++) {
            float4 w = *(const float4*)&Ws[k * 52 + c4 * 4];
            acc[c4 * 4 + 0] = fmaf(xv, w.x, acc[c4 * 4 + 0]);
            acc[c4 * 4 + 1] = fmaf(xv, w.y, acc[c4 * 4 + 1]);
            acc[c4 * 4 + 2] = fmaf(xv, w.z, acc[c4 * 4 + 2]);
            acc[c4 * 4 + 3] = fmaf(xv, w.w, acc[c4 * 4 + 3]);
        }
    }
    float* hr = h + (size_t)n * LD;
#pragma unroll
    for (int c4 = 0; c4 < 13; c4++) {
        float4 o;
        o.x = acc[c4 * 4 + 0]; o.y = acc[c4 * 4 + 1];
        o.z = acc[c4 * 4 + 2]; o.w = acc[c4 * 4 + 3];
        *(float4*)&hr[c4 * 4] = o;
    }
    float4 zz = make_float4(0.f, 0.f, 0.f, 0.f);
    *(float4*)&hr[52] = zz;
    *(float4*)&hr[56] = zz;
    *(float4*)&hr[60] = zz;
}

// One wave per node; lane = padded column; register accumulate; no LDS.
// BN+ReLU of the previous layer folded into the gather (and the self term).
template <bool BN_IN>
__global__ void k_agg(const float* __restrict__ hin, float* __restrict__ zout,
                      const int* __restrict__ rowptr, const int* __restrict__ csr,
                      const float* __restrict__ gam, const float* __restrict__ bet,
                      const float* __restrict__ stats, float invN,
                      const float* __restrict__ eps_gin, int l, int N) {
    int wave = threadIdx.x >> 6;
    int lane = threadIdx.x & 63;
    int n = blockIdx.x * 4 + wave;
    if (n >= N) return;
    float scr = 1.f, shr = 0.f;
    if (BN_IN) {
        if (lane < DV) {
            float mu = stats[lane] * invN;
            float var = stats[64 + lane] * invN - mu * mu;
            float s = gam[lane] * rsqrtf(var + 1e-5f);
            scr = s;
            shr = bet[lane] - mu * s;
        } else {
            scr = 0.f;
            shr = 0.f;
        }
    }
    int s = rowptr[n], e = rowptr[n + 1];
    float acc = 0.f;
    int deg = e - s;
    for (int base = 0; base < deg; base += 64) {
        int m = min(64, deg - base);
        int sv = (lane < m) ? csr[s + base + lane] : 0;
        int i = 0;
        for (; i + 8 <= m; i += 8) {
            int s0 = __shfl(sv, i), s1 = __shfl(sv, i + 1);
            int s2 = __shfl(sv, i + 2), s3 = __shfl(sv, i + 3);
            int s4 = __shfl(sv, i + 4), s5 = __shfl(sv, i + 5);
            int s6 = __shfl(sv, i + 6), s7 = __shfl(sv, i + 7);
            float v0 = hin[(size_t)s0 * LD + lane];
            float v1 = hin[(size_t)s1 * LD + lane];
            float v2 = hin[(size_t)s2 * LD + lane];
            float v3 = hin[(size_t)s3 * LD + lane];
            float v4 = hin[(size_t)s4 * LD + lane];
            float v5 = hin[(size_t)s5 * LD + lane];
            float v6 = hin[(size_t)s6 * LD + lane];
            float v7 = hin[(size_t)s7 * LD + lane];
            if (BN_IN) {
                v0 = fmaxf(0.f, fmaf(v0, scr, shr));
                v1 = fmaxf(0.f, fmaf(v1, scr, shr));
                v2 = fmaxf(0.f, fmaf(v2, scr, shr));
                v3 = fmaxf(0.f, fmaf(v3, scr, shr));
                v4 = fmaxf(0.f, fmaf(v4, scr, shr));
                v5 = fmaxf(0.f, fmaf(v5, scr, shr));
                v6 = fmaxf(0.f, fmaf(v6, scr, shr));
                v7 = fmaxf(0.f, fmaf(v7, scr, shr));
            }
            acc += v0 + v1 + v2 + v3 + v4 + v5 + v6 + v7;
        }
        for (; i < m; i++) {
            int sidx = __shfl(sv, i);
            float v = hin[(size_t)sidx * LD + lane];
            if (BN_IN) v = fmaxf(0.f, fmaf(v, scr, shr));
            acc += v;
        }
    }
    float eps1 = 1.f + eps_gin[l];
    float self = hin[(size_t)n * LD + lane];
    if (BN_IN) self = fmaxf(0.f, fmaf(self, scr, shr));
    zout[(size_t)n * LD + lane] = acc + eps1 * self;
}

// One thread per row; input row preloaded to registers (13x float4). Optional BN+ReLU of
// the input (stats of the previous linear); column sum/sumsq of output for the next BN.
template <bool BN_IN>
__global__ __launch_bounds__(256, 2)
void k_gemm(const float* in, float* out,
            const float* __restrict__ W, const float* __restrict__ bias,
            const float* __restrict__ gam, const float* __restrict__ bet,
            const float* __restrict__ statsIn, float* __restrict__ statsOut,
            float invN, int N) {
    __shared__ __align__(16) float Ws[DV * 52];
    __shared__ float pb[52];
    __shared__ float sc[DV], sh[DV];
    int t = threadIdx.x;
    for (int i = t; i < DV * 52; i += 256) {
        int k = i / 52, c = i - k * 52;
        Ws[i] = (c < DV) ? W[k * DV + c] : 0.f;
    }
    for (int i = t; i < 52; i += 256) pb[i] = (i < DV) ? bias[i] : 0.f;
    if (BN_IN) {
        if (t < DV) {
            float mu = statsIn[t] * invN;
            float var = statsIn[64 + t] * invN - mu * mu;
            float s = gam[t] * rsqrtf(var + 1e-5f);
            sc[t] = s;
            sh[t] = bet[t] - mu * s;
        }
    }
    __syncthreads();
    int n = blockIdx.x * 256 + t;
    bool active = (n < N);
    float row[52];
    if (active) {
        const float* rp = in + (size_t)n * LD;
#pragma unroll
        for (int q = 0; q < 13; q++) {
            float4 v = *(const float4*)&rp[q * 4];
            row[q * 4 + 0] = v.x; row[q * 4 + 1] = v.y;
            row[q * 4 + 2] = v.z; row[q * 4 + 3] = v.w;
        }
        if (BN_IN) {
#pragma unroll
            for (int k = 0; k < DV; k++) row[k] = fmaxf(0.f, fmaf(row[k], sc[k], sh[k]));
        }
    } else {
#pragma unroll
        for (int q = 0; q < 52; q++) row[q] = 0.f;
    }
    float acc[52];
#pragma unroll
    for (int c = 0; c < 52; c++) acc[c] = pb[c];
#pragma unroll
    for (int k = 0; k < DV; k++) {
        float xv = row[k];
#pragma unroll
        for (int c4 = 0; c4 < 13; c4++) {
            float4 w = *(const float4*)&Ws[k * 52 + c4 * 4];
            acc[c4 * 4 + 0] = fmaf(xv, w.x, acc[c4 * 4 + 0]);
            acc[c4 * 4 + 1] = fmaf(xv, w.y, acc[c4 * 4 + 1]);
            acc[c4 * 4 + 2] = fmaf(xv, w.z, acc[c4 * 4 + 2]);
            acc[c4 * 4 + 3] = fmaf(xv, w.w, acc[c4 * 4 + 3]);
        }
    }
    if (active) {
        float* orow = out + (size_t)n * LD;
#pragma unroll
        for (int c4 = 0; c4 < 13; c4++) {
            float4 o;
            o.x = acc[c4 * 4 + 0]; o.y = acc[c4 * 4 + 1];
            o.z = acc[c4 * 4 + 2]; o.w = acc[c4 * 4 + 3];
            *(float4*)&orow[c4 * 4] = o;
        }
        float4 zz = make_float4(0.f, 0.f, 0.f, 0.f);
        *(float4*)&orow[52] = zz;
        *(float4*)&orow[56] = zz;
        *(float4*)&orow[60] = zz;
    }
    // wave butterfly per column; lane c keeps column c's totals; 2 atomics/wave.
    float myS = 0.f, myQ = 0.f;
    int lane = t & 63;
#pragma unroll
    for (int c = 0; c < DV; c++) {
        float v = active ? acc[c] : 0.f;
        float s = v, q = v * v;
#pragma unroll
        for (int off = 32; off > 0; off >>= 1) {
            s += __shfl_xor(s, off);
            q += __shfl_xor(q, off);
        }
        if (lane == c) { myS = s; myQ = q; }
    }
    if (lane < DV) {
        atomicAdd(&statsOut[lane], myS);
        atomicAdd(&statsOut[64 + lane], myQ);
    }
}

// batch sorted: one wave per graph, binary search range, fold final BN+ReLU.
__global__ void k_pool(const float* __restrict__ h, const int* __restrict__ batch,
                       const float* __restrict__ gam, const float* __restrict__ bet,
                       const float* __restrict__ stats, float invN,
                       float* __restrict__ out, int N) {
    int g = blockIdx.x;
    int lane = threadIdx.x;
    int lo, hi;
    {
        int a = 0, b = N;
        while (a < b) { int mid = (a + b) >> 1; if (batch[mid] < g) a = mid + 1; else b = mid; }
        lo = a;
    }
    {
        int a = lo, b = N;
        while (a < b) { int mid = (a + b) >> 1; if (batch[mid] < g + 1) a = mid + 1; else b = mid; }
        hi = a;
    }
    float scv = 0.f, shv = 0.f;
    if (lane < DV) {
        float mu = stats[lane] * invN;
        float var = stats[64 + lane] * invN - mu * mu;
        float s = gam[lane] * rsqrtf(var + 1e-5f);
        scv = s;
        shv = bet[lane] - mu * s;
    }
    float a0 = 0.f, a1 = 0.f, a2 = 0.f, a3 = 0.f;
    int n2 = lo;
    for (; n2 + 4 <= hi; n2 += 4) {
        a0 += fmaxf(0.f, fmaf(h[(size_t)(n2 + 0) * LD + lane], scv, shv));
        a1 += fmaxf(0.f, fmaf(h[(size_t)(n2 + 1) * LD + lane], scv, shv));
        a2 += fmaxf(0.f, fmaf(h[(size_t)(n2 + 2) * LD + lane], scv, shv));
        a3 += fmaxf(0.f, fmaf(h[(size_t)(n2 + 3) * LD + lane], scv, shv));
    }
    for (; n2 < hi; n2++)
        a0 += fmaxf(0.f, fmaf(h[(size_t)n2 * LD + lane], scv, shv));
    float acc = (a0 + a1) + (a2 + a3);
    float cnt = (float)max(hi - lo, 1);
    if (lane < DV) out[g * DV + lane] = acc / cnt;
}

extern "C" void kernel_launch(void* const* d_in, const int* in_sizes, int n_in,
                              void* d_out, int out_size, void* d_ws, size_t ws_size,
                              hipStream_t stream) {
    const float* x = (const float*)d_in[0];
    const float* W0 = (const float*)d_in[1];
    const float* b0 = (const float*)d_in[2];
    const float* W1 = (const float*)d_in[3];
    const float* b1 = (const float*)d_in[4];
    const float* g1 = (const float*)d_in[5];
    const float* be1 = (const float*)d_in[6];
    const float* W2 = (const float*)d_in[7];
    const float* b2 = (const float*)d_in[8];
    const float* g2 = (const float*)d_in[9];
    const float* be2 = (const float*)d_in[10];
    const float* eps_gin = (const float*)d_in[11];
    const int* edge_index = (const int*)d_in[12];
    const int* batch = (const int*)d_in[13];
    float* out = (float*)d_out;

    int N = in_sizes[0] / DIN;
    int E = in_sizes[12] / 2;
    const int* esrc = edge_index;
    const int* edst = edge_index + E;
    int NB = (N + BSZ - 1) >> BSH;

    char* ws = (char*)d_ws;
    size_t off = 0;
    auto alloc = [&](size_t bytes) -> void* {
        void* p = ws + off;
        off = (off + bytes + 255) & ~(size_t)255;
        return p;
    };
    float* P = (float*)alloc((size_t)N * LD * 4);   // activations (ping)
    float* A = (float*)alloc((size_t)N * LD * 4);   // activations (pong)
    unsigned int* ep = (unsigned int*)alloc((size_t)E * 4);
    int* csr = (int*)alloc((size_t)E * 4);
    int* rowptr = (int*)alloc((size_t)(N + 1) * 4);
    int* ghist = (int*)alloc((size_t)NB * 4);
    int* bstart = (int*)alloc((size_t)(NB + 1) * 4);
    int* cursor = (int*)alloc((size_t)NB * 4);
    float* stats = (float*)alloc(NLAY * 2 * 128 * 4);
    (void)ws_size;  // needs ~65 MB

    float invN = 1.f / (float)N;
    int gN = (N + 255) / 256;

    k_zero<<<8, 256, 0, stream>>>(ghist, NB, stats);
    k_hist_b<<<1024, 256, 0, stream>>>(edst, E, ghist, NB);
    k_scanb<<<1, 256, 0, stream>>>(ghist, NB, bstart, cursor);
    k_scatter_b<<<256, 256, 0, stream>>>(esrc, edst, E, cursor, ep, NB);
    k_sortb<<<NB, 256, 0, stream>>>(ep, bstart, csr, rowptr, N, NB);
    k_lin0<<<gN, 256, 0, stream>>>(x, W0, b0, P, N);

    for (int l = 0; l < NLAY; l++) {
        float* S1 = stats + (l * 2 + 0) * 128;
        float* S2 = stats + (l * 2 + 1) * 128;
        if (l == 0) {
            k_agg<false><<<(N + 3) / 4, 256, 0, stream>>>(P, A, rowptr, csr, nullptr,
                                                          nullptr, nullptr, invN,
                                                          eps_gin, l, N);
        } else {
            float* S2p = stats + ((l - 1) * 2 + 1) * 128;
            k_agg<true><<<(N + 3) / 4, 256, 0, stream>>>(P, A, rowptr, csr,
                                                         g2 + (l - 1) * DV,
                                                         be2 + (l - 1) * DV, S2p, invN,
                                                         eps_gin, l, N);
        }
        k_gemm<false><<<gN, 256, 0, stream>>>(A, A, W1 + (size_t)l * DV * DV, b1 + l * DV,
                                              nullptr, nullptr, nullptr, S1, invN, N);
        k_gemm<true><<<gN, 256, 0, stream>>>(A, P, W2 + (size_t)l * DV * DV, b2 + l * DV,
                                             g1 + l * DV, be1 + l * DV, S1, S2, invN, N);
    }
    float* S2last = stats + ((NLAY - 1) * 2 + 1) * 128;
    k_pool<<<NGR, 64, 0, stream>>>(P, batch, g2 + (NLAY - 1) * DV, be2 + (NLAY - 1) * DV,
                                   S2last, invN, out, N);
}